// Round 8
// baseline (938.043 us; speedup 1.0000x reference)
//
#include <hip/hip_runtime.h>
#include <math.h>

// WaveLM: logits[b,t,v] = sum_{t'<t} g(id[b,t'], v)
// g(u,v) = 2 * sum_{i,j in 1..H} (A_u/i^dec)(A_v/j^dec) * sinc(2*(f_u*i - f_v*j))
// sinc(2d) = sin(2*pi*d)/(2*pi*d), sinc(0)=1
//
// R8: R5-verified math (angle-addition + Montgomery batch inversion, packed
// fp32 inline asm) with two structural changes:
//  1) u-side (wave-uniform) operands via readfirstlane + addrspace(4) loads
//     -> s_load into SGPR pairs, consumed as the 1-SGPR operand of v_pk_*.
//     Frees ~42 VGPRs (R7's occupancy collapse) and offloads latency to the
//     scalar pipe.
//  2) single-pass prefix via decoupled look-back: each block (one 8-token
//     segment x 512-v tile) keeps local exclusive prefixes in LDS, publishes
//     its aggregate (agent-scope atomics + release flag), sums predecessors'
//     aggregates/inclusives (acquire), writes base+local directly. No scan
//     kernels, no 128 MB +base pass. Aggregates publish before any wait ->
//     forward progress regardless of residency; dispatch is in linear block
//     order so predecessors dispatch first.

typedef float v2f __attribute__((ext_vector_type(2)));
typedef unsigned long long u64;
typedef __attribute__((address_space(4))) const u64 cu64;

constexpr int cB = 4, cT = 512, cV = 8000, cH = 7;
constexpr int GT = 8;                  // tokens per block = segment length
constexpr int NSEG = 64;               // cT / GT
constexpr int VT = 16;                 // v-tiles (512 v each)
// tab planes: 0-6 s | 7-13 c | 14-20 w | 21-27 b | 28-34 nb | 35-41 sBw | 42-48 cBw
constexpr int TABP  = 49;
constexpr int TABUP = 21;              // tabU (v2f dup): 0-6 aU | 7-13 2ws | 14-20 -2wc

__device__ __forceinline__ v2f pk_add(v2f a, v2f b) {
    v2f d; asm("v_pk_add_f32 %0, %1, %2" : "=v"(d) : "v"(a), "v"(b)); return d;
}
__device__ __forceinline__ v2f pk_mul(v2f a, v2f b) {
    v2f d; asm("v_pk_mul_f32 %0, %1, %2" : "=v"(d) : "v"(a), "v"(b)); return d;
}
__device__ __forceinline__ void pk_mul_ip(v2f& a, v2f b) {          // a *= b
    asm("v_pk_mul_f32 %0, %0, %1" : "+v"(a) : "v"(b));
}
__device__ __forceinline__ void pk_acc(v2f& acc, v2f a, v2f b) {    // acc += a*b
    asm("v_pk_fma_f32 %0, %1, %2, %0" : "+v"(acc) : "v"(a), "v"(b));
}
__device__ __forceinline__ v2f pk_add_sv(u64 a, v2f b) {            // s-pair src
    v2f d; asm("v_pk_add_f32 %0, %1, %2" : "=v"(d) : "s"(a), "v"(b)); return d;
}
__device__ __forceinline__ void pk_acc_sv(v2f& acc, u64 a, v2f b) { // acc += s*b
    asm("v_pk_fma_f32 %0, %1, %2, %0" : "+v"(acc) : "s"(a), "v"(b));
}

__global__ __launch_bounds__(256) void wavelm_tab(
    const float* __restrict__ freq, const float* __restrict__ amp,
    const float* __restrict__ decay_p, float* __restrict__ tab,
    v2f* __restrict__ tabU)
{
    const int v = blockIdx.x * 256 + threadIdx.x;
    if (v >= cV) return;
    const float decay = decay_p[0];
    const float f = freq[v], A = amp[v];
    const float p2 = __builtin_amdgcn_exp2f(-decay);
    const float p3 = __builtin_amdgcn_exp2f(-decay * 1.5849625007f);
    const float p5 = __builtin_amdgcn_exp2f(-decay * 2.3219280949f);
    const float p7 = __builtin_amdgcn_exp2f(-decay * 2.8073549221f);
    const float rp[7] = {1.f, p2, p3, p2*p2, p5, p2*p3, p7};
    const float INV2PI = 0.15915494309189535f;

    const float xr = f - rintf(f);
    const float s1 = __builtin_amdgcn_sinf(xr);
    const float c1 = __builtin_amdgcn_cosf(xr);
    float s = s1, c = c1;
#pragma unroll
    for (int k = 0; k < cH; ++k) {
        if (k) { const float sp = s, cp = c;
                 s = fmaf(sp, c1,  cp * s1);
                 c = fmaf(cp, c1, -(sp * s1)); }
        const float w = A * rp[k];
        const float b = f * (float)(k + 1);
        tab[(size_t)k * cV + v]        = s;
        tab[(size_t)(7 + k) * cV + v]  = c;
        tab[(size_t)(14 + k) * cV + v] = w;
        tab[(size_t)(21 + k) * cV + v] = b;
        tab[(size_t)(28 + k) * cV + v] = -b;
        tab[(size_t)(35 + k) * cV + v] = s * w * INV2PI;
        tab[(size_t)(42 + k) * cV + v] = c * w * INV2PI;
        v2f a2;  a2.x = b;             a2.y = b;
        v2f s2;  s2.x = 2.f * w * s;   s2.y = s2.x;
        v2f c2;  c2.x = -2.f * w * c;  c2.y = c2.x;
        tabU[(size_t)k * cV + v]        = a2;
        tabU[(size_t)(7 + k) * cV + v]  = s2;
        tabU[(size_t)(14 + k) * cV + v] = c2;
    }
}

__global__ __launch_bounds__(256) void wavelm_zero(unsigned* __restrict__ p, int n)
{
    const int i = blockIdx.x * 256 + threadIdx.x;
    if (i < n) p[i] = 0u;
}

__global__ __launch_bounds__(256) void wavelm_g(
    const int* __restrict__ ids, const float* __restrict__ tab,
    const v2f* __restrict__ tabU, float* __restrict__ out,
    float* __restrict__ part, u64* __restrict__ agg, u64* __restrict__ incl,
    unsigned* __restrict__ flags, int mode)
{
    __shared__ v2f lds[GT * 256];

    const int vt  = blockIdx.x;
    const int y   = blockIdx.y;                  // b*NSEG + seg
    const int seg = y & (NSEG - 1);
    const int bt0 = y * GT;
    const int tid = threadIdx.x;
    const int vh  = vt * 256 + tid;
    const bool valid = (vh * 2 < cV);
    const int vc = valid ? vh : 0;
    const int v0 = vh * 2;

    const v2f* tp = (const v2f*)tab;             // plane k at k*(cV/2)+vc
    v2f nb[cH], sBw[cH], cBw[cH];
#pragma unroll
    for (int j = 0; j < cH; ++j) {
        nb[j]  = tp[(size_t)(28 + j) * (cV/2) + vc];
        sBw[j] = tp[(size_t)(35 + j) * (cV/2) + vc];
        cBw[j] = tp[(size_t)(42 + j) * (cV/2) + vc];
    }

    v2f segacc = (v2f)0.f;
#pragma unroll 1
    for (int g = 0; g < GT; ++g) {
        const int bt = bt0 + g;
        const int id = __builtin_amdgcn_readfirstlane(ids[bt]);
        cu64* tu = (cu64*)(unsigned long long)(const void*)(tabU + id);
        u64 aU[cH], us[cH], ucn[cH];
#pragma unroll
        for (int i = 0; i < cH; ++i) {
            aU[i]  = tu[(size_t)i * cV];
            us[i]  = tu[(size_t)(7 + i) * cV];
            ucn[i] = tu[(size_t)(14 + i) * cV];
        }

        v2f accV = (v2f)0.f;
        float mn = 3.0e38f, mx = 0.0f;
#pragma unroll
        for (int i = 0; i < cH; ++i) {
            v2f d[cH], p[cH];
#pragma unroll
            for (int j = 0; j < cH; ++j) d[j] = pk_add_sv(aU[i], nb[j]);
            p[0] = d[0];
#pragma unroll
            for (int j = 1; j < cH; ++j) p[j] = pk_mul(p[j-1], d[j]);
            const float ptot = p[6].x * p[6].y;
            mn = fminf(mn, fabsf(ptot));
            mx = fmaxf(mx, fabsf(ptot));
            const float rt = __builtin_amdgcn_rcpf(ptot);
            v2f r;  r.x = rt * p[6].y;  r.y = rt * p[6].x;   // 1/p6 per comp
            v2f inv = pk_mul(r, p[5]);
            v2f accS = pk_mul(cBw[6], inv);
            v2f accC = pk_mul(sBw[6], inv);
            pk_mul_ip(r, d[6]);
#pragma unroll
            for (int j = 5; j >= 1; --j) {
                inv = pk_mul(r, p[j-1]);
                pk_acc(accS, cBw[j], inv);
                pk_acc(accC, sBw[j], inv);
                pk_mul_ip(r, d[j]);
            }
            pk_acc(accS, cBw[0], r);
            pk_acc(accC, sBw[0], r);
            pk_acc_sv(accV, us[i],  accS);       // += (2 wA sA) * accS
            pk_acc_sv(accV, ucn[i], accC);       // += (-2 wA cA) * accC
        }

        // rare guarded redo: exact d==0 (v==id), product under/overflow, nan
        if (mn < 1e-37f || !(mx <= 1e37f) ||
            !(fabsf(accV.x) + fabsf(accV.y) < 1e37f)) {
            const float INV2PI = 0.15915494309189535f;
            float ax = 0.f, ay = 0.f;
#pragma unroll
            for (int i = 0; i < cH; ++i) {
                const float sAi = tab[(size_t)i * cV + id];
                const float cAi = tab[(size_t)(7 + i) * cV + id];
                const float wAi = tab[(size_t)(14 + i) * cV + id];
                const float aUi = tab[(size_t)(21 + i) * cV + id];
                float rx = 0.f, ry = 0.f;
#pragma unroll
                for (int j = 0; j < cH; ++j) {
                    const v2f sB = tp[(size_t)j * (cV/2) + vc];
                    const v2f cB = tp[(size_t)(7 + j) * (cV/2) + vc];
                    const v2f wB = tp[(size_t)(14 + j) * (cV/2) + vc];
                    const v2f bb = tp[(size_t)(21 + j) * (cV/2) + vc];
                    const float dx = aUi - bb.x;
                    const float dy = aUi - bb.y;
                    const float snx = fmaf(sAi, cB.x, -(cAi * sB.x));
                    const float sny = fmaf(sAi, cB.y, -(cAi * sB.y));
                    float qx = snx * INV2PI * __builtin_amdgcn_rcpf(dx);
                    float qy = sny * INV2PI * __builtin_amdgcn_rcpf(dy);
                    qx = (dx == 0.f) ? 1.f : qx;
                    qy = (dy == 0.f) ? 1.f : qy;
                    rx = fmaf(wB.x, qx, rx);
                    ry = fmaf(wB.y, qy, ry);
                }
                ax = fmaf(2.f * wAi, rx, ax);
                ay = fmaf(2.f * wAi, ry, ay);
            }
            accV.x = ax;  accV.y = ay;
        }

        if (mode == 2) {
            lds[g * 256 + tid] = segacc;         // local exclusive prefix
        } else if (valid) {
            *(v2f*)(out + (size_t)bt * cV + v0) = accV;
        }
        segacc = pk_add(segacc, accV);
    }

    if (mode == 2) {
        const int st_self = y * VT + vt;
        v2f base = (v2f)0.f;
        if (seg == 0) {
            __hip_atomic_store(&incl[(size_t)st_self * 256 + tid],
                               __builtin_bit_cast(u64, segacc),
                               __ATOMIC_RELAXED, __HIP_MEMORY_SCOPE_AGENT);
            __syncthreads();
            if (tid == 0)
                __hip_atomic_store(&flags[st_self], 2u,
                                   __ATOMIC_RELEASE, __HIP_MEMORY_SCOPE_AGENT);
        } else {
            __hip_atomic_store(&agg[(size_t)st_self * 256 + tid],
                               __builtin_bit_cast(u64, segacc),
                               __ATOMIC_RELAXED, __HIP_MEMORY_SCOPE_AGENT);
            __syncthreads();
            if (tid == 0)
                __hip_atomic_store(&flags[st_self], 1u,
                                   __ATOMIC_RELEASE, __HIP_MEMORY_SCOPE_AGENT);
            // look-back with aggregate fallback (no serial chain, no deadlock)
            int s = seg - 1;
            while (true) {
                const int st_p = (y - (seg - s)) * VT + vt;
                const unsigned fl = __hip_atomic_load(
                    &flags[st_p], __ATOMIC_ACQUIRE, __HIP_MEMORY_SCOPE_AGENT);
                if (fl == 2u) {
                    const u64 t = __hip_atomic_load(
                        &incl[(size_t)st_p * 256 + tid],
                        __ATOMIC_RELAXED, __HIP_MEMORY_SCOPE_AGENT);
                    base = pk_add(base, __builtin_bit_cast(v2f, t));
                    break;
                } else if (fl == 1u) {
                    const u64 t = __hip_atomic_load(
                        &agg[(size_t)st_p * 256 + tid],
                        __ATOMIC_RELAXED, __HIP_MEMORY_SCOPE_AGENT);
                    base = pk_add(base, __builtin_bit_cast(v2f, t));
                    if (--s < 0) break;
                } else {
                    __builtin_amdgcn_s_sleep(2);
                }
            }
            if (seg < NSEG - 1) {                // last segment has no reader
                const v2f inc = pk_add(base, segacc);
                __hip_atomic_store(&incl[(size_t)st_self * 256 + tid],
                                   __builtin_bit_cast(u64, inc),
                                   __ATOMIC_RELAXED, __HIP_MEMORY_SCOPE_AGENT);
                __syncthreads();
                if (tid == 0)
                    __hip_atomic_store(&flags[st_self], 2u,
                                       __ATOMIC_RELEASE, __HIP_MEMORY_SCOPE_AGENT);
            }
        }
        if (valid) {
#pragma unroll
            for (int g = 0; g < GT; ++g) {
                const v2f val = pk_add(base, lds[g * 256 + tid]);
                *(v2f*)(out + (size_t)(bt0 + g) * cV + v0) = val;
            }
        }
    } else if (mode == 1 && valid) {
        *(v2f*)(part + (size_t)y * cV + v0) = segacc;
    }
}

// ---- fallback scan kernels (ws too small for look-back state) ----
__global__ __launch_bounds__(256) void wavelm_scanA(float* __restrict__ part)
{
    const int g = blockIdx.x * 256 + threadIdx.x;
    if (g >= cB * cV) return;
    const int b = g / cV;
    const int v = g - b * cV;
    float acc = 0.f;
#pragma unroll 8
    for (int s = 0; s < NSEG; ++s) {
        const size_t idx = ((size_t)(b * NSEG + s)) * cV + v;
        const float t = part[idx];
        part[idx] = acc;
        acc += t;
    }
}

__global__ __launch_bounds__(256) void wavelm_scanB(
    float* __restrict__ out, const float* __restrict__ part)
{
    const int v = blockIdx.x * 256 + threadIdx.x;
    if (v >= cV) return;
    const int grp = blockIdx.y;
    float acc = part[(size_t)grp * cV + v];
    float* p = out + (size_t)grp * GT * cV + v;
#pragma unroll
    for (int k = 0; k < GT; ++k) {
        const float c = p[(size_t)k * cV];
        p[(size_t)k * cV] = acc;
        acc += c;
    }
}

__global__ __launch_bounds__(256) void wavelm_scan(float* __restrict__ out)
{
    const int g = blockIdx.x * blockDim.x + threadIdx.x;
    if (g >= cB * cV) return;
    const int b = g / cV;
    const int v = g - b * cV;
    float* p = out + (size_t)b * cT * cV + v;
    float acc = 0.f;
#pragma unroll 8
    for (int t = 0; t < cT; ++t) {
        const float c = p[(size_t)t * cV];
        p[(size_t)t * cV] = acc;
        acc += c;
    }
}

extern "C" void kernel_launch(void* const* d_in, const int* in_sizes, int n_in,
                              void* d_out, int out_size, void* d_ws, size_t ws_size,
                              hipStream_t stream)
{
    const int*   ids  = (const int*)d_in[0];
    const float* freq = (const float*)d_in[1];
    const float* amp  = (const float*)d_in[2];
    const float* dec  = (const float*)d_in[3];
    float* out = (float*)d_out;

    char* wsp = (char*)d_ws;
    const size_t tab_b   = (size_t)TABP * cV * sizeof(float);     // 1,568,000
    const size_t tabu_b  = (size_t)TABUP * cV * sizeof(v2f);      // 1,344,000
    const size_t nstate  = (size_t)cB * NSEG * VT;                // 4096
    const size_t flags_b = nstate * sizeof(unsigned);
    const size_t agg_b   = nstate * 256 * sizeof(u64);            // 8,388,608
    const size_t part_b  = (size_t)cB * NSEG * cV * sizeof(float);

    float*    tab   = (float*)wsp;
    v2f*      tabU  = (v2f*)(wsp + tab_b);
    unsigned* flags = (unsigned*)(wsp + tab_b + tabu_b);
    u64*      agg   = (u64*)(wsp + tab_b + tabu_b + flags_b);
    u64*      incl  = (u64*)(wsp + tab_b + tabu_b + flags_b + agg_b);
    float*    part  = (float*)(wsp + tab_b + tabu_b);             // mode-1 alias

    int mode;
    if (ws_size >= tab_b + tabu_b + flags_b + 2 * agg_b)       mode = 2;
    else if (ws_size >= tab_b + tabu_b + part_b)               mode = 1;
    else                                                       mode = 0;

    wavelm_tab<<<(cV + 255) / 256, 256, 0, stream>>>(freq, amp, dec, tab, tabU);
    if (mode == 2)
        wavelm_zero<<<((int)nstate + 255) / 256, 256, 0, stream>>>(flags, (int)nstate);

    dim3 grid(VT, cB * NSEG);                    // 16 x 256, seg-major dispatch
    wavelm_g<<<grid, dim3(256), 0, stream>>>(ids, tab, tabU, out, part,
                                             agg, incl, flags, mode);

    if (mode == 1) {
        const int nchains = cB * cV;
        wavelm_scanA<<<(nchains + 255) / 256, 256, 0, stream>>>(part);
        dim3 sb((cV + 255) / 256, cB * NSEG);
        wavelm_scanB<<<sb, dim3(256), 0, stream>>>(out, part);
    } else if (mode == 0) {
        const int nchains = cB * cV;
        wavelm_scan<<<(nchains + 255) / 256, dim3(256), 0, stream>>>(out);
    }
}